// Round 2
// baseline (682.833 us; speedup 1.0000x reference)
//
#include <hip/hip_runtime.h>

// Problem dims
#define Bn   256
#define Tn   1024
#define INn  128
#define Hn   10
#define OUTn 128
#define BTn  (Bn * Tn)   // 262144 rows

// =====================================================================
// K1: xp0[b,t,j] = sum_i x[b,t,i]*W_ih0[j,i] + b_ih0[j] + b_hh0[j]
// Stored padded to 16 floats per row (j in [10,16) = 0) for K2's
// coalesced lane loads. One thread per (b,t) row; W_ih0 staged in LDS
// (uniform-address broadcast reads, no bank conflicts).
// =====================================================================
__global__ __launch_bounds__(256) void k1_inproj(
    const float* __restrict__ x,
    const float* __restrict__ Wih0,
    const float* __restrict__ bih0,
    const float* __restrict__ bhh0,
    float* __restrict__ xp0)
{
    __shared__ float Ws[Hn][INn];   // 5 KB
    __shared__ float bs[16];
    const int tid = threadIdx.x;
    for (int idx = tid; idx < Hn * INn; idx += 256)
        Ws[idx / INn][idx % INn] = Wih0[idx];
    if (tid < 16) bs[tid] = (tid < Hn) ? (bih0[tid] + bhh0[tid]) : 0.f;
    __syncthreads();

    const int row = blockIdx.x * 256 + tid;                 // grid = BTn/256
    const float4* xr = reinterpret_cast<const float4*>(x + (size_t)row * INn);

    float acc[Hn];
    #pragma unroll
    for (int j = 0; j < Hn; ++j) acc[j] = bs[j];

    #pragma unroll
    for (int c = 0; c < INn / 4; ++c) {
        float4 v = xr[c];
        #pragma unroll
        for (int j = 0; j < Hn; ++j) {
            acc[j] = fmaf(v.x, Ws[j][c * 4 + 0], acc[j]);
            acc[j] = fmaf(v.y, Ws[j][c * 4 + 1], acc[j]);
            acc[j] = fmaf(v.z, Ws[j][c * 4 + 2], acc[j]);
            acc[j] = fmaf(v.w, Ws[j][c * 4 + 3], acc[j]);
        }
    }
    float4* op = reinterpret_cast<float4*>(xp0 + (size_t)row * 16);
    op[0] = make_float4(acc[0], acc[1], acc[2], acc[3]);
    op[1] = make_float4(acc[4], acc[5], acc[6], acc[7]);
    op[2] = make_float4(acc[8], acc[9], 0.f, 0.f);
    op[3] = make_float4(0.f, 0.f, 0.f, 0.f);
}

// =====================================================================
// K2: the sequential recurrence, software-pipelined across layers.
// 64 lanes = 2 chains x 32 lanes. Within a 32-lane chain group:
//   lanes 0..15  ("half 0") hold h1[j], weights A=W_hh0 row j, B=0
//   lanes 16..31 ("half 1") hold h2[j] (one step behind),
//                weights A=W_ih1 row j, B=W_hh1 row j
// Iteration t computes h1[t] (half0) and h2[t-1] (half1) concurrently,
// sharing broadcasts: shfl(h,k,32)=h1[t-1][k], shfl(h,16+k,32)=h2[t-2][k].
// xp0 prefetched 8 steps ahead (ring of 8 registers).
// =====================================================================
__global__ __launch_bounds__(64) void k2_recur(
    const float* __restrict__ xp0,
    const float* __restrict__ Whh0,
    const float* __restrict__ Wih1,
    const float* __restrict__ Whh1,
    const float* __restrict__ bih1,
    const float* __restrict__ bhh1,
    float* __restrict__ h2seq,
    float* __restrict__ hidden)   // [2, Bn, Hn] f32 (tail of d_out)
{
    const int lane = threadIdx.x;          // 0..63
    const int half = (lane >> 4) & 1;
    const int j    = lane & 15;
    const int jc   = (j < Hn) ? j : (Hn - 1);
    const int b    = blockIdx.x * 2 + (lane >> 5);   // grid = Bn/2 = 128

    float Aw[Hn], Bw[Hn];
    #pragma unroll
    for (int k = 0; k < Hn; ++k) {
        Aw[k] = half ? Wih1[jc * Hn + k] : Whh0[jc * Hn + k];
        Bw[k] = half ? Whh1[jc * Hn + k] : 0.f;
    }
    const float bias1 = bih1[jc] + bhh1[jc];

    const float* xp  = xp0 + (size_t)b * Tn * 16 + j;
    float*       h2p = h2seq + (size_t)b * Tn * Hn + j;

    float h = 0.f;   // half0: h1 state; half1: h2 state (one step behind)

    float xbuf[8];
    #pragma unroll
    for (int u = 0; u < 8; ++u) xbuf[u] = xp[u * 16];

    for (int tb = 0; tb < Tn / 8; ++tb) {
        #pragma unroll
        for (int u = 0; u < 8; ++u) {
            const int t = tb * 8 + u;
            const float xv = xbuf[u];
            if (tb < Tn / 8 - 1) xbuf[u] = xp[(t + 8) * 16];
            const float base = half ? bias1 : xv;
            float c1a = 0.f, c1b = 0.f, c2a = 0.f, c2b = 0.f;
            #pragma unroll
            for (int k = 0; k < Hn; ++k) {
                const float h1k = __shfl(h, k, 32);        // h1[t-1][k]
                const float h2k = __shfl(h, 16 + k, 32);   // h2[t-2][k]
                if (k & 1) { c1b = fmaf(Aw[k], h1k, c1b); c2b = fmaf(Bw[k], h2k, c2b); }
                else       { c1a = fmaf(Aw[k], h1k, c1a); c2a = fmaf(Bw[k], h2k, c2a); }
            }
            const float hn = fmaxf(base + (c1a + c1b) + (c2a + c2b), 0.f);
            if (t == 0) {
                h = half ? 0.f : hn;      // h2 not yet defined at t=0
            } else {
                h = hn;                    // half0: h1[t]; half1: h2[t-1]
                if (half && j < Hn) h2p[(t - 1) * Hn] = hn;
            }
        }
    }
    // Epilogue: h2[T-1] = relu(bias1 + W_ih1*h1[T-1] + W_hh1*h2[T-2])
    {
        float c1a = 0.f, c1b = 0.f, c2a = 0.f, c2b = 0.f;
        #pragma unroll
        for (int k = 0; k < Hn; ++k) {
            const float h1k = __shfl(h, k, 32);
            const float h2k = __shfl(h, 16 + k, 32);
            if (k & 1) { c1b = fmaf(Aw[k], h1k, c1b); c2b = fmaf(Bw[k], h2k, c2b); }
            else       { c1a = fmaf(Aw[k], h1k, c1a); c2a = fmaf(Bw[k], h2k, c2a); }
        }
        const float hn = fmaxf(bias1 + (c1a + c1b) + (c2a + c2b), 0.f);
        if (half && j < Hn) {
            h2p[(Tn - 1) * Hn] = hn;
            hidden[Bn * Hn + b * Hn + j] = hn;   // hidden[1] = h2[T-1]
        }
        if (!half && j < Hn) {
            hidden[b * Hn + j] = h;              // hidden[0] = h1[T-1]
        }
    }
}

// =====================================================================
// K3: logits = h2seq * W_lin^T + b_lin, softmax over 128, f32 out.
// 16 lanes per row (4 rows/wave); lane i owns outputs o = i*8..i*8+7,
// W_lin rows persistent in registers (~80 VGPR). Grid-stride over rows.
// =====================================================================
__global__ __launch_bounds__(256) void k3_outproj(
    const float* __restrict__ h2seq,
    const float* __restrict__ Wlin,
    const float* __restrict__ blin,
    float* __restrict__ out)
{
    const int lane = threadIdx.x & 63;
    const int wid  = blockIdx.x * 4 + (threadIdx.x >> 6);  // grid=1024 -> 4096 waves
    const int g    = lane >> 4;
    const int i    = lane & 15;

    float wl[8][Hn], bl[8];
    #pragma unroll
    for (int s = 0; s < 8; ++s) {
        const int o = i * 8 + s;
        bl[s] = blin[o];
        #pragma unroll
        for (int k = 0; k < Hn; ++k) wl[s][k] = Wlin[o * Hn + k];
    }

    for (int r = wid * 4 + g; r < BTn; r += 4096 * 4) {
        const float hv = (i < Hn) ? h2seq[(size_t)r * Hn + i] : 0.f;
        float acc[8];
        #pragma unroll
        for (int s = 0; s < 8; ++s) acc[s] = bl[s];
        #pragma unroll
        for (int k = 0; k < Hn; ++k) {
            const float hk = __shfl(hv, k, 16);
            #pragma unroll
            for (int s = 0; s < 8; ++s) acc[s] = fmaf(wl[s][k], hk, acc[s]);
        }
        // softmax over this row's 128 logits (16 lanes x 8)
        float m = acc[0];
        #pragma unroll
        for (int s = 1; s < 8; ++s) m = fmaxf(m, acc[s]);
        #pragma unroll
        for (int off = 1; off < 16; off <<= 1) m = fmaxf(m, __shfl_xor(m, off, 16));
        float e[8], ssum = 0.f;
        #pragma unroll
        for (int s = 0; s < 8; ++s) { e[s] = __expf(acc[s] - m); ssum += e[s]; }
        #pragma unroll
        for (int off = 1; off < 16; off <<= 1) ssum += __shfl_xor(ssum, off, 16);
        const float inv = 1.0f / ssum;
        float4* op = reinterpret_cast<float4*>(out + (size_t)r * OUTn + i * 8);
        op[0] = make_float4(e[0] * inv, e[1] * inv, e[2] * inv, e[3] * inv);
        op[1] = make_float4(e[4] * inv, e[5] * inv, e[6] * inv, e[7] * inv);
    }
}

extern "C" void kernel_launch(void* const* d_in, const int* in_sizes, int n_in,
                              void* d_out, int out_size, void* d_ws, size_t ws_size,
                              hipStream_t stream)
{
    const float* x    = (const float*)d_in[0];
    const float* Wih0 = (const float*)d_in[1];
    const float* Whh0 = (const float*)d_in[2];
    const float* bih0 = (const float*)d_in[3];
    const float* bhh0 = (const float*)d_in[4];
    const float* Wih1 = (const float*)d_in[5];
    const float* Whh1 = (const float*)d_in[6];
    const float* bih1 = (const float*)d_in[7];
    const float* bhh1 = (const float*)d_in[8];
    const float* Wlin = (const float*)d_in[9];
    const float* blin = (const float*)d_in[10];

    float* out    = (float*)d_out;
    float* hidden = out + (size_t)BTn * OUTn;    // [2,B,H] tail of d_out

    float* xp0   = (float*)d_ws;                 // BTn*16 f32 = 16.8 MB
    float* h2seq = xp0 + (size_t)BTn * 16;       // BTn*10 f32 = 10.5 MB

    k1_inproj<<<BTn / 256, 256, 0, stream>>>(x, Wih0, bih0, bhh0, xp0);
    k2_recur<<<Bn / 2, 64, 0, stream>>>(xp0, Whh0, Wih1, Whh1, bih1, bhh1, h2seq, hidden);
    k3_outproj<<<1024, 256, 0, stream>>>(h2seq, Wlin, blin, out);
}

// Round 3
// 571.228 us; speedup vs baseline: 1.1954x; 1.1954x over previous
//
#include <hip/hip_runtime.h>

// Problem dims
#define Bn   256
#define Tn   1024
#define INn  128
#define Hn   10
#define OUTn 128
#define BTn  (Bn * Tn)   // 262144 rows

// =====================================================================
// K1: xp0[b,t,j] = sum_i x[b,t,i]*W_ih0[j,i] + b_ih0[j] + b_hh0[j]
// (unchanged from round 2 — controlled experiment; K2 is the variable)
// =====================================================================
__global__ __launch_bounds__(256) void k1_inproj(
    const float* __restrict__ x,
    const float* __restrict__ Wih0,
    const float* __restrict__ bih0,
    const float* __restrict__ bhh0,
    float* __restrict__ xp0)
{
    __shared__ float Ws[Hn][INn];   // 5 KB
    __shared__ float bs[16];
    const int tid = threadIdx.x;
    for (int idx = tid; idx < Hn * INn; idx += 256)
        Ws[idx / INn][idx % INn] = Wih0[idx];
    if (tid < 16) bs[tid] = (tid < Hn) ? (bih0[tid] + bhh0[tid]) : 0.f;
    __syncthreads();

    const int row = blockIdx.x * 256 + tid;                 // grid = BTn/256
    const float4* xr = reinterpret_cast<const float4*>(x + (size_t)row * INn);

    float acc[Hn];
    #pragma unroll
    for (int j = 0; j < Hn; ++j) acc[j] = bs[j];

    #pragma unroll
    for (int c = 0; c < INn / 4; ++c) {
        float4 v = xr[c];
        #pragma unroll
        for (int j = 0; j < Hn; ++j) {
            acc[j] = fmaf(v.x, Ws[j][c * 4 + 0], acc[j]);
            acc[j] = fmaf(v.y, Ws[j][c * 4 + 1], acc[j]);
            acc[j] = fmaf(v.z, Ws[j][c * 4 + 2], acc[j]);
            acc[j] = fmaf(v.w, Ws[j][c * 4 + 3], acc[j]);
        }
    }
    float4* op = reinterpret_cast<float4*>(xp0 + (size_t)row * 16);
    op[0] = make_float4(acc[0], acc[1], acc[2], acc[3]);
    op[1] = make_float4(acc[4], acc[5], acc[6], acc[7]);
    op[2] = make_float4(acc[8], acc[9], 0.f, 0.f);
    op[3] = make_float4(0.f, 0.f, 0.f, 0.f);
}

// =====================================================================
// K2 v2: recurrence with LDS state exchange instead of 20 bpermutes.
// Block = 1 wave = 2 chains. Per chain, LDS holds the 20-float state
// vector contiguously: [0..9]=h1[t-1], [10..19]=h2[t-2], [20..31]=junk
// (writes from the 6 inactive lanes per half land there harmlessly).
// Per step: 5x ds_read_b128 (wave-uniform addr per chain -> broadcast,
// 2 distinct addrs/wave = free) -> 20 FMA -> 1 ds_write_b32 of new
// state. DS ops execute in wave order, so no barrier needed (1 wave).
// Layer 2 pipelined one step behind layer 1 as before:
//   lanes 0..15 ("half 0"): h1[t][j], A=W_hh0 row j, B=0
//   lanes 16..31 ("half 1"): h2[t-1][j], A=W_ih1 row j, B=W_hh1 row j
// __launch_bounds__(64,1): allow the allocator plenty of VGPRs so the
// reads/FMAs keep 20 live values (round-2 lesson: VGPR=40 serialized
// the 20 bpermutes at ~47 cyc each = 944 cyc/step).
// =====================================================================
__global__ __launch_bounds__(64, 1) void k2_recur(
    const float* __restrict__ xp0,
    const float* __restrict__ Whh0,
    const float* __restrict__ Wih1,
    const float* __restrict__ Whh1,
    const float* __restrict__ bih1,
    const float* __restrict__ bhh1,
    float* __restrict__ h2seq,
    float* __restrict__ hidden)   // [2, Bn, Hn] f32 (tail of d_out)
{
    const int lane = threadIdx.x;          // 0..63
    const int half = (lane >> 4) & 1;
    const int j    = lane & 15;
    const int jc   = (j < Hn) ? j : (Hn - 1);
    const int c    = lane >> 5;            // chain within block
    const int b    = blockIdx.x * 2 + c;   // grid = Bn/2 = 128

    __shared__ float state[2][32];         // 256 B
    state[c][lane & 31] = 0.f;             // zero-init both chains' slots

    float Aw[Hn], Bw[Hn];
    #pragma unroll
    for (int k = 0; k < Hn; ++k) {
        Aw[k] = half ? Wih1[jc * Hn + k] : Whh0[jc * Hn + k];
        Bw[k] = half ? Whh1[jc * Hn + k] : 0.f;
    }
    const float bias1 = bih1[jc] + bhh1[jc];

    // per-lane write slot: active lanes -> h1[j] / h2[j]; inactive -> junk
    const int wslot = (j < Hn) ? (half * Hn + j) : (20 + half * 6 + (j - Hn));
    float* const wptr  = &state[c][wslot];
    const float* const rbase = &state[c][0];

    const float* xp  = xp0 + (size_t)b * Tn * 16 + j;
    float*       h2w = h2seq + (size_t)b * Tn * Hn + j - Hn;  // pre-offset by -Hn: step t stores t-1

    float h = 0.f;   // half0 keeps h1[t] for hidden[0]

    float xbuf[8];
    #pragma unroll
    for (int u = 0; u < 8; ++u) xbuf[u] = xp[u * 16];

    for (int tb = 0; tb < Tn / 8; ++tb) {
        #pragma unroll
        for (int u = 0; u < 8; ++u) {
            const int t = tb * 8 + u;
            const float xv = xbuf[u];
            if (tb < Tn / 8 - 1) xbuf[u] = xp[(u + 8) * 16];

            // gather state: g[0..9]=h1[t-1], g[10..19]=h2[t-2]
            float4 q0 = *reinterpret_cast<const float4*>(rbase + 0);
            float4 q1 = *reinterpret_cast<const float4*>(rbase + 4);
            float4 q2 = *reinterpret_cast<const float4*>(rbase + 8);
            float4 q3 = *reinterpret_cast<const float4*>(rbase + 12);
            float4 q4 = *reinterpret_cast<const float4*>(rbase + 16);
            const float g[20] = {q0.x,q0.y,q0.z,q0.w, q1.x,q1.y,q1.z,q1.w,
                                 q2.x,q2.y,q2.z,q2.w, q3.x,q3.y,q3.z,q3.w,
                                 q4.x,q4.y,q4.z,q4.w};

            const float base = half ? bias1 : xv;
            float c1a = 0.f, c1b = 0.f, c2a = 0.f, c2b = 0.f;
            #pragma unroll
            for (int k = 0; k < Hn; ++k) {
                if (k & 1) { c1b = fmaf(Aw[k], g[k], c1b); c2b = fmaf(Bw[k], g[10 + k], c2b); }
                else       { c1a = fmaf(Aw[k], g[k], c1a); c2a = fmaf(Bw[k], g[10 + k], c2a); }
            }
            const float hn = fmaxf(base + (c1a + c1b) + (c2a + c2b), 0.f);

            // at t==0, half1's result is h2[-1] (undefined) -> keep state 0
            const float wval = (half && t == 0) ? 0.f : hn;
            *wptr = wval;
            h = wval;   // half0: h1[t]; half1: h2[t-1]

            if (half && (j < Hn) && t > 0) h2w[0] = hn;   // h2seq[b, t-1, j]
            h2w += Hn;
        }
        xp += 128;   // advance 8 timesteps (16 floats each)
    }

    // Epilogue: h2[T-1] = relu(bias1 + W_ih1*h1[T-1] + W_hh1*h2[T-2])
    {
        float4 q0 = *reinterpret_cast<const float4*>(rbase + 0);
        float4 q1 = *reinterpret_cast<const float4*>(rbase + 4);
        float4 q2 = *reinterpret_cast<const float4*>(rbase + 8);
        float4 q3 = *reinterpret_cast<const float4*>(rbase + 12);
        float4 q4 = *reinterpret_cast<const float4*>(rbase + 16);
        const float g[20] = {q0.x,q0.y,q0.z,q0.w, q1.x,q1.y,q1.z,q1.w,
                             q2.x,q2.y,q2.z,q2.w, q3.x,q3.y,q3.z,q3.w,
                             q4.x,q4.y,q4.z,q4.w};
        float c1a = 0.f, c1b = 0.f, c2a = 0.f, c2b = 0.f;
        #pragma unroll
        for (int k = 0; k < Hn; ++k) {
            if (k & 1) { c1b = fmaf(Aw[k], g[k], c1b); c2b = fmaf(Bw[k], g[10 + k], c2b); }
            else       { c1a = fmaf(Aw[k], g[k], c1a); c2a = fmaf(Bw[k], g[10 + k], c2a); }
        }
        const float hn = fmaxf(bias1 + (c1a + c1b) + (c2a + c2b), 0.f);
        if (half && j < Hn) {
            h2w[0] = hn;                           // h2seq[b, T-1, j]
            hidden[Bn * Hn + b * Hn + j] = hn;     // hidden[1] = h2[T-1]
        }
        if (!half && j < Hn) {
            hidden[b * Hn + j] = h;                // hidden[0] = h1[T-1]
        }
    }
}

// =====================================================================
// K3: logits = h2seq * W_lin^T + b_lin, softmax over 128, f32 out.
// (unchanged from round 2)
// =====================================================================
__global__ __launch_bounds__(256) void k3_outproj(
    const float* __restrict__ h2seq,
    const float* __restrict__ Wlin,
    const float* __restrict__ blin,
    float* __restrict__ out)
{
    const int lane = threadIdx.x & 63;
    const int wid  = blockIdx.x * 4 + (threadIdx.x >> 6);  // grid=1024 -> 4096 waves
    const int g    = lane >> 4;
    const int i    = lane & 15;

    float wl[8][Hn], bl[8];
    #pragma unroll
    for (int s = 0; s < 8; ++s) {
        const int o = i * 8 + s;
        bl[s] = blin[o];
        #pragma unroll
        for (int k = 0; k < Hn; ++k) wl[s][k] = Wlin[o * Hn + k];
    }

    for (int r = wid * 4 + g; r < BTn; r += 4096 * 4) {
        const float hv = (i < Hn) ? h2seq[(size_t)r * Hn + i] : 0.f;
        float acc[8];
        #pragma unroll
        for (int s = 0; s < 8; ++s) acc[s] = bl[s];
        #pragma unroll
        for (int k = 0; k < Hn; ++k) {
            const float hk = __shfl(hv, k, 16);
            #pragma unroll
            for (int s = 0; s < 8; ++s) acc[s] = fmaf(wl[s][k], hk, acc[s]);
        }
        // softmax over this row's 128 logits (16 lanes x 8)
        float m = acc[0];
        #pragma unroll
        for (int s = 1; s < 8; ++s) m = fmaxf(m, acc[s]);
        #pragma unroll
        for (int off = 1; off < 16; off <<= 1) m = fmaxf(m, __shfl_xor(m, off, 16));
        float e[8], ssum = 0.f;
        #pragma unroll
        for (int s = 0; s < 8; ++s) { e[s] = __expf(acc[s] - m); ssum += e[s]; }
        #pragma unroll
        for (int off = 1; off < 16; off <<= 1) ssum += __shfl_xor(ssum, off, 16);
        const float inv = 1.0f / ssum;
        float4* op = reinterpret_cast<float4*>(out + (size_t)r * OUTn + i * 8);
        op[0] = make_float4(e[0] * inv, e[1] * inv, e[2] * inv, e[3] * inv);
        op[1] = make_float4(e[4] * inv, e[5] * inv, e[6] * inv, e[7] * inv);
    }
}

extern "C" void kernel_launch(void* const* d_in, const int* in_sizes, int n_in,
                              void* d_out, int out_size, void* d_ws, size_t ws_size,
                              hipStream_t stream)
{
    const float* x    = (const float*)d_in[0];
    const float* Wih0 = (const float*)d_in[1];
    const float* Whh0 = (const float*)d_in[2];
    const float* bih0 = (const float*)d_in[3];
    const float* bhh0 = (const float*)d_in[4];
    const float* Wih1 = (const float*)d_in[5];
    const float* Whh1 = (const float*)d_in[6];
    const float* bih1 = (const float*)d_in[7];
    const float* bhh1 = (const float*)d_in[8];
    const float* Wlin = (const float*)d_in[9];
    const float* blin = (const float*)d_in[10];

    float* out    = (float*)d_out;
    float* hidden = out + (size_t)BTn * OUTn;    // [2,B,H] tail of d_out

    float* xp0   = (float*)d_ws;                 // BTn*16 f32 = 16.8 MB
    float* h2seq = xp0 + (size_t)BTn * 16;       // BTn*10 f32 = 10.5 MB

    k1_inproj<<<BTn / 256, 256, 0, stream>>>(x, Wih0, bih0, bhh0, xp0);
    k2_recur<<<Bn / 2, 64, 0, stream>>>(xp0, Whh0, Wih1, Whh1, bih1, bhh1, h2seq, hidden);
    k3_outproj<<<1024, 256, 0, stream>>>(h2seq, Wlin, blin, out);
}